// Round 14
// baseline (142.785 us; speedup 1.0000x reference)
//
#include <hip/hip_runtime.h>

typedef __bf16 bf16x8 __attribute__((ext_vector_type(8)));
typedef float f32x4 __attribute__((ext_vector_type(4)));
typedef float f32x16 __attribute__((ext_vector_type(16)));
typedef unsigned short u16x8 __attribute__((ext_vector_type(8)));

constexpr int S_LEN = 2048;
constexpr int QKV1  = 2 * 16 * 2048 * 64;   // elements per Q/K/V tensor = 4194304

__device__ inline unsigned short f2bf(float f) {
    __bf16 h = (__bf16)f;
    return __builtin_bit_cast(unsigned short, h);
}

__device__ inline void gll16(const void* g, void* l) {
    __builtin_amdgcn_global_load_lds(
        (const __attribute__((address_space(1))) unsigned int*)g,
        (__attribute__((address_space(3))) unsigned int*)l,
        16, 0, 0);
}

// ---------------------------------------------------------------------------
// fp32 -> bf16 convert (for X).
// ---------------------------------------------------------------------------
__global__ __launch_bounds__(256) void cvt_f32_bf16(
    const float* __restrict__ src, unsigned short* __restrict__ dst, int n4)
{
    int i = blockIdx.x * 256 + threadIdx.x;
    if (i >= n4) return;
    float4 v = ((const float4*)src)[i];
    ushort4 u;
    u.x = f2bf(v.x); u.y = f2bf(v.y); u.z = f2bf(v.z); u.w = f2bf(v.w);
    ((ushort4*)dst)[i] = u;
}

// ---------------------------------------------------------------------------
// Transpose + convert: src [R][C] fp32 -> dst [C][R] bf16
// ---------------------------------------------------------------------------
__global__ __launch_bounds__(256) void transpose_cvt(
    const float* __restrict__ src, unsigned short* __restrict__ dst, int R, int C)
{
    __shared__ float t[32][33];
    const int c0 = blockIdx.x * 32, r0 = blockIdx.y * 32;
    const int tx = threadIdx.x, ty = threadIdx.y;
    #pragma unroll
    for (int i = 0; i < 4; ++i)
        t[ty * 4 + i][tx] = src[(size_t)(r0 + ty * 4 + i) * C + c0 + tx];
    __syncthreads();
    #pragma unroll
    for (int i = 0; i < 4; ++i)
        dst[(size_t)(c0 + ty * 4 + i) * R + r0 + tx] = f2bf(t[tx][ty * 4 + i]);
}

// ---------------------------------------------------------------------------
// 256x256 4-phase/K-tile GEMM (QKV projection, EPI-0 scatter epilogue).
// RACE-FREE redesign: phases split by K-HALF (= what each phase reads).
// LDS [2 slot][2 kh][256][32] per operand (128KB). Per K-tile j (slot s=j&1):
//  ph1: read B(kh0)+A mi0-3(kh0) | stage A-k0(j+1)      | bar | 16 MFMA | bar
//  ph2: read A mi4-7(kh0), B reused | stage B-k0(j+1)   | bar | 16 MFMA | vmcnt(4) bar
//  ph3: read B(kh1)+A mi0-3(kh1) | stage A-k1(j+1)      | bar | 16 MFMA | bar
//  ph4: read A mi4-7(kh1)        | stage B-k1(j+1)      | bar | 16 MFMA | vmcnt(4) bar
// Per-wave drain ledger (2 loads/stage): entering tile j outstanding =
// {A-k1(s),B-k1(s)}; ph2's vmcnt(4) drains exactly those (read by ph3);
// ph4's vmcnt(4) drains {A-k0,B-k0}(s^1) (read by tile j+1 ph1). Tail: vmcnt(0)
// at last tile's ph2. sched_barrier(0) pins ds_reads below drain-barriers.
// Swizzle both-sides: store slot (l&3)^((l>>3)&3), read slot g^((q>>1)&3)
// -> 2-way reads (free, m136).
// ---------------------------------------------------------------------------
__global__ __launch_bounds__(512) void gemm256(
    const unsigned short* __restrict__ A,   // [M][K] bf16
    const unsigned short* __restrict__ Bt,  // [N][K] bf16
    const float* __restrict__ bias,         // [N]
    unsigned short* __restrict__ qkv, int M, int N, int K)
{
    extern __shared__ unsigned short lds[];
    unsigned short* AsL = lds;              // [2][2][256*32]
    unsigned short* BsL = lds + 32768;      // [2][2][256*32]
    const int tid = threadIdx.x, lane = tid & 63, wid = tid >> 6;
    const int q = lane & 15, g = lane >> 4;
    const int wm = wid >> 2, wn = wid & 3;
    const int nbx = N >> 8;                 // 12
    const int cpx = gridDim.x >> 3;
    const int bid = blockIdx.x;
    const int swz = (bid & 7) * cpx + (bid >> 3);   // bijective, 192%8==0
    const int m0 = (swz / nbx) * 256, n0 = (swz % nbx) * 256;

    // stage addressing: lane l -> LDS (row base+l>>2, slot l&3);
    // source global col slot = (l&3)^((l>>3)&3)  [= (l&3)^((row>>1)&3)]
    const int rl = lane >> 2;
    const int sl = (((lane & 3) ^ ((lane >> 3) & 3))) * 8;
    auto stA = [&](int slot, int kh, int k0) {      // 2 gll16/wave: rows wid*32..+31
        const unsigned short* sp = &A[(size_t)(m0 + wid * 32 + rl) * K + k0 + kh * 32 + sl];
        unsigned short* d = &AsL[((slot * 2 + kh) * 256 + wid * 32) * 32];
        gll16(sp, d);
        gll16(sp + (size_t)16 * K, d + 16 * 32);
    };
    auto stB = [&](int slot, int kh, int k0) {
        const unsigned short* sp = &Bt[(size_t)(n0 + wid * 32 + rl) * K + k0 + kh * 32 + sl];
        unsigned short* d = &BsL[((slot * 2 + kh) * 256 + wid * 32) * 32];
        gll16(sp, d);
        gll16(sp + (size_t)16 * K, d + 16 * 32);
    };

    f32x4 acc[8][4];
    #pragma unroll
    for (int i = 0; i < 8; ++i)
        #pragma unroll
        for (int j = 0; j < 4; ++j) acc[i][j] = (f32x4){0.f, 0.f, 0.f, 0.f};

    const int kq = (q >> 1) & 3;            // read-side swizzle component
    const int rcol = (g ^ kq) * 8;          // read col within [32]
    const int NSTEP = K >> 6;               // 16

    // prologue: tile 0's four stage-halves in ledger order; drain first two
    stA(0, 0, 0); stB(0, 0, 0); stA(0, 1, 0); stB(0, 1, 0);
    asm volatile("s_waitcnt vmcnt(4)" ::: "memory");
    __builtin_amdgcn_s_barrier();
    __builtin_amdgcn_sched_barrier(0);

    for (int j = 0; j < NSTEP; ++j) {
        const int s = j & 1;
        const bool pf = (j + 1 < NSTEP);
        const int kn = (j + 1) * 64;
        const size_t abase = (size_t)(s * 2) * 8192;          // kh=0 region
        const size_t abase1 = abase + 8192;                   // kh=1 region
        bf16x8 a[4], b[4];
        // ---------------- ph1: kh0, mi0-3 ----------------
        #pragma unroll
        for (int ni = 0; ni < 4; ++ni)
            b[ni] = *(const bf16x8*)&BsL[abase + (size_t)(wn * 64 + ni * 16 + q) * 32 + rcol];
        #pragma unroll
        for (int mi = 0; mi < 4; ++mi)
            a[mi] = *(const bf16x8*)&AsL[abase + (size_t)(wm * 128 + mi * 16 + q) * 32 + rcol];
        if (pf) stA(s ^ 1, 0, kn);
        __builtin_amdgcn_s_barrier();
        __builtin_amdgcn_s_setprio(1);
        #pragma unroll
        for (int mi = 0; mi < 4; ++mi)
            #pragma unroll
            for (int ni = 0; ni < 4; ++ni)
                acc[mi][ni] = __builtin_amdgcn_mfma_f32_16x16x32_bf16(a[mi], b[ni], acc[mi][ni], 0, 0, 0);
        __builtin_amdgcn_s_setprio(0);
        __builtin_amdgcn_s_barrier();
        // ---------------- ph2: kh0, mi4-7 (B reused) ----------------
        #pragma unroll
        for (int mi = 0; mi < 4; ++mi)
            a[mi] = *(const bf16x8*)&AsL[abase + (size_t)(wm * 128 + (mi + 4) * 16 + q) * 32 + rcol];
        if (pf) stB(s ^ 1, 0, kn);
        __builtin_amdgcn_s_barrier();
        __builtin_amdgcn_s_setprio(1);
        #pragma unroll
        for (int mi = 0; mi < 4; ++mi)
            #pragma unroll
            for (int ni = 0; ni < 4; ++ni)
                acc[mi + 4][ni] = __builtin_amdgcn_mfma_f32_16x16x32_bf16(a[mi], b[ni], acc[mi + 4][ni], 0, 0, 0);
        __builtin_amdgcn_s_setprio(0);
        if (pf) asm volatile("s_waitcnt vmcnt(4)" ::: "memory");  // drains {A-k1,B-k1}(s)
        else    asm volatile("s_waitcnt vmcnt(0)" ::: "memory");
        __builtin_amdgcn_s_barrier();
        __builtin_amdgcn_sched_barrier(0);
        // ---------------- ph3: kh1, mi0-3 ----------------
        #pragma unroll
        for (int ni = 0; ni < 4; ++ni)
            b[ni] = *(const bf16x8*)&BsL[abase1 + (size_t)(wn * 64 + ni * 16 + q) * 32 + rcol];
        #pragma unroll
        for (int mi = 0; mi < 4; ++mi)
            a[mi] = *(const bf16x8*)&AsL[abase1 + (size_t)(wm * 128 + mi * 16 + q) * 32 + rcol];
        if (pf) stA(s ^ 1, 1, kn);
        __builtin_amdgcn_s_barrier();
        __builtin_amdgcn_s_setprio(1);
        #pragma unroll
        for (int mi = 0; mi < 4; ++mi)
            #pragma unroll
            for (int ni = 0; ni < 4; ++ni)
                acc[mi][ni] = __builtin_amdgcn_mfma_f32_16x16x32_bf16(a[mi], b[ni], acc[mi][ni], 0, 0, 0);
        __builtin_amdgcn_s_setprio(0);
        __builtin_amdgcn_s_barrier();
        // ---------------- ph4: kh1, mi4-7 (B reused) ----------------
        #pragma unroll
        for (int mi = 0; mi < 4; ++mi)
            a[mi] = *(const bf16x8*)&AsL[abase1 + (size_t)(wm * 128 + (mi + 4) * 16 + q) * 32 + rcol];
        if (pf) stB(s ^ 1, 1, kn);
        __builtin_amdgcn_s_barrier();
        __builtin_amdgcn_s_setprio(1);
        #pragma unroll
        for (int mi = 0; mi < 4; ++mi)
            #pragma unroll
            for (int ni = 0; ni < 4; ++ni)
                acc[mi + 4][ni] = __builtin_amdgcn_mfma_f32_16x16x32_bf16(a[mi], b[ni], acc[mi + 4][ni], 0, 0, 0);
        __builtin_amdgcn_s_setprio(0);
        if (pf) {
            asm volatile("s_waitcnt vmcnt(4)" ::: "memory");      // drains {A-k0,B-k0}(s^1)
            __builtin_amdgcn_s_barrier();
            __builtin_amdgcn_sched_barrier(0);
        }
    }

    // ---- epilogue: qkv scatter (verified EPI-0 mapping) ----
    #pragma unroll
    for (int mi = 0; mi < 8; ++mi)
        #pragma unroll
        for (int ni = 0; ni < 4; ++ni)
            #pragma unroll
            for (int r = 0; r < 4; ++r) {
                int m = m0 + wm * 128 + mi * 16 + g * 4 + r;
                int n = n0 + wn * 64 + ni * 16 + q;
                float v = acc[mi][ni][r] + bias[n];
                int t = n >> 10, rem = n & 1023;
                if (t == 0) v *= 0.125f;          // q * rsqrt(64)
                int h2 = rem >> 6, kk = rem & 63;
                int bb = m >> 11, s2 = m & 2047;
                size_t off;
                if (t == 2)   // V transposed: Vt[bh][d][s]
                    off = 2 * (size_t)QKV1 + ((size_t)(bb * 16 + h2) * 64 + kk) * 2048 + s2;
                else          // Q/K: [bh][s][d]
                    off = (size_t)t * QKV1 + ((size_t)(bb * 16 + h2) * 2048 + s2) * 64 + kk;
                qkv[off] = f2bf(v);
            }
}

// ---------------------------------------------------------------------------
// bf16 GEMM 128^2, 2-phase (unchanged — output projection).
// ---------------------------------------------------------------------------
template<int EPI>
__global__ __launch_bounds__(256) void gemm128(
    const unsigned short* __restrict__ A, const unsigned short* __restrict__ Bt,
    const float* __restrict__ bias, void* __restrict__ outp, int M, int N, int K)
{
    __shared__ unsigned short As[2][128 * 32];
    __shared__ unsigned short Bs[2][128 * 32];
    const int tid = threadIdx.x, lane = tid & 63, wid = tid >> 6;
    const int q = lane & 15, g = lane >> 4;
    const int wr = wid >> 1, wc = wid & 1;

    const int nbx = N >> 7;
    const int cpx = gridDim.x >> 3;
    const int bid = blockIdx.x;
    const int swz = (bid & 7) * cpx + (bid >> 3);
    const int m0 = (swz / nbx) * 128, n0 = (swz % nbx) * 128;

    const int srow_in = lane >> 2;
    const int sslot   = (lane & 3) ^ (srow_in & 3);
    auto stage = [&](int buf, int k0) {
        #pragma unroll
        for (int i = 0; i < 2; ++i) {
            int c = wid * 2 + i;
            int row = c * 16 + srow_in;
            gll16(&A [(size_t)(m0 + row) * K + k0 + sslot * 8], &As[buf][c * 512]);
            gll16(&Bt[(size_t)(n0 + row) * K + k0 + sslot * 8], &Bs[buf][c * 512]);
        }
    };

    f32x4 acc[4][4];
    #pragma unroll
    for (int i = 0; i < 4; ++i)
        #pragma unroll
        for (int j = 0; j < 4; ++j) acc[i][j] = (f32x4){0.f, 0.f, 0.f, 0.f};

    const int NSTEP = K >> 5;
    const int rslot = (g ^ (q & 3)) * 8;
    stage(0, 0);
    __syncthreads();
    int cur = 0;

    for (int ks = 0; ks < NSTEP; ++ks) {
        if (ks + 1 < NSTEP) stage(cur ^ 1, (ks + 1) * 32);
        bf16x8 a[4], b[4];
        #pragma unroll
        for (int mi = 0; mi < 4; ++mi)
            a[mi] = *(const bf16x8*)&As[cur][(wr * 64 + mi * 16 + q) * 32 + rslot];
        #pragma unroll
        for (int ni = 0; ni < 4; ++ni)
            b[ni] = *(const bf16x8*)&Bs[cur][(wc * 64 + ni * 16 + q) * 32 + rslot];
        #pragma unroll
        for (int mi = 0; mi < 4; ++mi)
            #pragma unroll
            for (int ni = 0; ni < 4; ++ni)
                acc[mi][ni] = __builtin_amdgcn_mfma_f32_16x16x32_bf16(a[mi], b[ni], acc[mi][ni], 0, 0, 0);
        __syncthreads();
        cur ^= 1;
    }

    #pragma unroll
    for (int mi = 0; mi < 4; ++mi)
        #pragma unroll
        for (int ni = 0; ni < 4; ++ni)
            #pragma unroll
            for (int r = 0; r < 4; ++r) {
                int m = m0 + wr * 64 + mi * 16 + g * 4 + r;
                int n = n0 + wc * 64 + ni * 16 + q;
                float v = acc[mi][ni][r] + bias[n];
                if (EPI == 0) {
                    int t = n >> 10, rem = n & 1023;
                    if (t == 0) v *= 0.125f;
                    int h2 = rem >> 6, kk = rem & 63;
                    int bb = m >> 11, s = m & 2047;
                    size_t off;
                    if (t == 2)
                        off = 2 * (size_t)QKV1 + ((size_t)(bb * 16 + h2) * 64 + kk) * 2048 + s;
                    else
                        off = (size_t)t * QKV1 + ((size_t)(bb * 16 + h2) * 2048 + s) * 64 + kk;
                    ((unsigned short*)outp)[off] = f2bf(v);
                } else {
                    ((float*)outp)[(size_t)m * N + n] = v;
                }
            }
}

// ---------------------------------------------------------------------------
// Kernel 2: causal flash attention, KV-SPLIT (unchanged — known-good).
// ---------------------------------------------------------------------------
__global__ __launch_bounds__(256) void attn_fwd(
    const unsigned short* __restrict__ qkv,
    unsigned short* __restrict__ po, float2* __restrict__ pml)
{
    __shared__ unsigned short Ks[2][64][72];
    __shared__ unsigned short Vs[2][64][72];
    __shared__ float cLds[4][32];
    const int tid = threadIdx.x, lane = tid & 63, wid = tid >> 6;
    const int hi = lane >> 5, lq = lane & 31;
    const int bh = blockIdx.x;
    const int uy = (int)blockIdx.y;
    const int t    = 15 - (uy >> 1);
    const int half = uy & 1;
    const int jb0 = half ? (t + 1) : 0;
    const int jb1 = half ? (2 * t + 2) : (t + 1);
    const unsigned short* Qg = qkv + (size_t)bh * S_LEN * 64;
    const unsigned short* Kg = qkv + (size_t)QKV1 + (size_t)bh * S_LEN * 64;
    const unsigned short* Vt = qkv + 2 * (size_t)QKV1 + (size_t)bh * 64 * S_LEN;

    const int srr = tid >> 3, scc = (tid & 7) * 8;
    u16x8 kr[2], vr[2];
    auto stage_load = [&](int j0) {
        #pragma unroll
        for (int p = 0; p < 2; ++p) {
            kr[p] = *(const u16x8*)&Kg[(size_t)(j0 + srr + p * 32) * 64 + scc];
            vr[p] = *(const u16x8*)&Vt[(size_t)(srr + p * 32) * 2048 + j0 + scc];
        }
    };
    auto stage_write = [&](int b) {
        #pragma unroll
        for (int p = 0; p < 2; ++p) {
            *(u16x8*)&Ks[b][srr + p * 32][scc] = kr[p];
            *(u16x8*)&Vs[b][srr + p * 32][scc] = vr[p];
        }
    };

    const int qbase = t * 128 + wid * 32;
    const int qg = qbase + lq;

    bf16x8 qf[4];
    #pragma unroll
    for (int kc = 0; kc < 4; ++kc)
        qf[kc] = *(const bf16x8*)&Qg[(size_t)qg * 64 + kc * 16 + hi * 8];

    f32x16 z16;
    #pragma unroll
    for (int j = 0; j < 16; ++j) z16[j] = 0.f;

    f32x16 o0 = z16, o1 = z16;
    float m = -1e30f, lr = 0.f;

    stage_load(jb0 * 64);
    stage_write(0);
    int cur = 0;

    for (int jb = jb0; jb < jb1; ++jb) {
        const int j0 = jb * 64;
        if (jb + 1 < jb1) stage_load(j0 + 64);
        __syncthreads();

        if (j0 <= qbase + 31) {
            f32x16 s0, s1;
            __builtin_amdgcn_s_setprio(1);
            {
                bf16x8 k0 = *(const bf16x8*)&Ks[cur][lq][hi * 8];
                bf16x8 k1 = *(const bf16x8*)&Ks[cur][32 + lq][hi * 8];
                s0 = __builtin_amdgcn_mfma_f32_32x32x16_bf16(k0, qf[0], z16, 0, 0, 0);
                s1 = __builtin_amdgcn_mfma_f32_32x32x16_bf16(k1, qf[0], z16, 0, 0, 0);
            }
            #pragma unroll
            for (int kc = 1; kc < 4; ++kc) {
                bf16x8 k0 = *(const bf16x8*)&Ks[cur][lq][kc * 16 + hi * 8];
                bf16x8 k1 = *(const bf16x8*)&Ks[cur][32 + lq][kc * 16 + hi * 8];
                s0 = __builtin_amdgcn_mfma_f32_32x32x16_bf16(k0, qf[kc], s0, 0, 0, 0);
                s1 = __builtin_amdgcn_mfma_f32_32x32x16_bf16(k1, qf[kc], s1, 0, 0, 0);
            }
            __builtin_amdgcn_s_setprio(0);
            if (j0 + 63 > qbase) {
                #pragma unroll
                for (int r = 0; r < 16; ++r) {
                    int kv0 = j0 + (r & 3) + 8 * (r >> 2) + 4 * hi;
                    if (kv0 > qg)      s0[r] = -1e30f;
                    if (kv0 + 32 > qg) s1[r] = -1e30f;
                }
            }
            float tm[8];
            #pragma unroll
            for (int j = 0; j < 8; ++j)
                tm[j] = fmaxf(fmaxf(s0[j], s0[j + 8]), fmaxf(s1[j], s1[j + 8]));
            float pm_loc = fmaxf(fmaxf(fmaxf(tm[0], tm[1]), fmaxf(tm[2], tm[3])),
                                 fmaxf(fmaxf(tm[4], tm[5]), fmaxf(tm[6], tm[7])));
            if (!__all(pm_loc <= m + 8.0f)) {
                float pm = fmaxf(pm_loc, __shfl_xor(pm_loc, 32));
                float mn = fmaxf(m, pm);
                float corr = __expf(m - mn);
                m = mn; lr *= corr;
                if (lane < 32) cLds[wid][lq] = corr;
                #pragma unroll
                for (int r = 0; r < 16; ++r) {
                    float cq = cLds[wid][(r & 3) + 8 * (r >> 2) + 4 * hi];
                    o0[r] *= cq; o1[r] *= cq;
                }
            }
            float p0[16], p1[16], ts[16];
            #pragma unroll
            for (int j = 0; j < 16; ++j) {
                p0[j] = __expf(s0[j] - m);
                p1[j] = __expf(s1[j] - m);
                ts[j] = p0[j] + p1[j];
            }
            #pragma unroll
            for (int w = 8; w > 0; w >>= 1)
                #pragma unroll
                for (int j = 0; j < w; ++j) ts[j] += ts[j + w];
            lr += ts[0];
            int w0[8], w1[8];
            #pragma unroll
            for (int j = 0; j < 8; ++j) {
                asm("v_cvt_pk_bf16_f32 %0, %1, %2" : "=v"(w0[j]) : "v"(p0[2 * j]), "v"(p0[2 * j + 1]));
                asm("v_cvt_pk_bf16_f32 %0, %1, %2" : "=v"(w1[j]) : "v"(p1[2 * j]), "v"(p1[2 * j + 1]));
            }
            bf16x8 pa[4];
            auto mkfrag = [&](const int* w, int base) -> bf16x8 {
                int x0 = __shfl_xor(w[base + 0], 32);
                int x1 = __shfl_xor(w[base + 1], 32);
                int x2 = __shfl_xor(w[base + 2], 32);
                int x3 = __shfl_xor(w[base + 3], 32);
                int4 f;
                f.x = hi ? x2          : w[base + 0];
                f.y = hi ? x3          : w[base + 1];
                f.z = hi ? w[base + 2] : x0;
                f.w = hi ? w[base + 3] : x1;
                return __builtin_bit_cast(bf16x8, f);
            };
            pa[0] = mkfrag(w0, 0);
            pa[1] = mkfrag(w0, 4);
            pa[2] = mkfrag(w1, 0);
            pa[3] = mkfrag(w1, 4);
            __builtin_amdgcn_s_setprio(1);
            #pragma unroll
            for (int kc = 0; kc < 4; ++kc) {
                bf16x8 v0 = *(const bf16x8*)&Vs[cur][lq][kc * 16 + hi * 8];
                bf16x8 v1 = *(const bf16x8*)&Vs[cur][32 + lq][kc * 16 + hi * 8];
                o0 = __builtin_amdgcn_mfma_f32_32x32x16_bf16(pa[kc], v0, o0, 0, 0, 0);
                o1 = __builtin_amdgcn_mfma_f32_32x32x16_bf16(pa[kc], v1, o1, 0, 0, 0);
            }
            __builtin_amdgcn_s_setprio(0);
        }

        if (jb + 1 < jb1) stage_write(cur ^ 1);
        cur ^= 1;
    }

    const int unit = (bh * 16 + t) * 2 + half;
    float lr_full = lr + __shfl_xor(lr, 32);
    if (lane < 32) {
        float2 v; v.x = m; v.y = lr_full;
        pml[unit * 128 + wid * 32 + lq] = v;
    }
    #pragma unroll
    for (int r = 0; r < 16; ++r) {
        int lrow = wid * 32 + (r & 3) + 8 * (r >> 2) + 4 * hi;
        size_t off = ((size_t)unit * 128 + lrow) * 64;
        po[off + lq]      = f2bf(o0[r]);
        po[off + 32 + lq] = f2bf(o1[r]);
    }
}

// ---------------------------------------------------------------------------
// Combine: merge the two KV-halves per q-row (unchanged).
// ---------------------------------------------------------------------------
__global__ __launch_bounds__(256) void attn_combine(
    const unsigned short* __restrict__ po, const float2* __restrict__ pml,
    unsigned short* __restrict__ aout)
{
    const int gid = blockIdx.x * 256 + threadIdx.x;
    const int row = gid >> 2;
    const int cg  = (gid & 3) * 16;
    const int bt = row >> 7, lrow = row & 127;
    const float2 ml0 = pml[(bt * 2 + 0) * 128 + lrow];
    const float2 ml1 = pml[(bt * 2 + 1) * 128 + lrow];
    const float ms = fmaxf(ml0.x, ml1.x);
    float w0 = __expf(ml0.x - ms), w1 = __expf(ml1.x - ms);
    const float inv = 1.0f / (ml0.y * w0 + ml1.y * w1);
    w0 *= inv; w1 *= inv;
    const size_t r0 = ((size_t)(bt * 2 + 0) * 128 + lrow) * 64 + cg;
    const size_t r1 = ((size_t)(bt * 2 + 1) * 128 + lrow) * 64 + cg;
    const int bh = bt >> 4, t = bt & 15;
    const int bb = bh >> 4, h = bh & 15;
    const int s = t * 128 + lrow;
    const size_t orow = ((size_t)(bb * 2048 + s)) * 1024 + h * 64 + cg;
    #pragma unroll
    for (int c = 0; c < 2; ++c) {
        u16x8 a = *(const u16x8*)&po[r0 + c * 8];
        u16x8 b = *(const u16x8*)&po[r1 + c * 8];
        u16x8 o;
        #pragma unroll
        for (int e = 0; e < 8; ++e) {
            float fa = __builtin_bit_cast(float, (unsigned)((unsigned short)a[e]) << 16);
            float fb = __builtin_bit_cast(float, (unsigned)((unsigned short)b[e]) << 16);
            o[e] = f2bf(fa * w0 + fb * w1);
        }
        *(u16x8*)&aout[orow + c * 8] = o;
    }
}

extern "C" void kernel_launch(void* const* d_in, const int* in_sizes, int n_in,
                              void* d_out, int out_size, void* d_ws, size_t ws_size,
                              hipStream_t stream) {
    const float* x     = (const float*)d_in[0];
    const float* Wqkv  = (const float*)d_in[2];
    const float* bqkv  = (const float*)d_in[3];
    const float* Wproj = (const float*)d_in[4];
    const float* bproj = (const float*)d_in[5];

    unsigned short* qkvb  = (unsigned short*)d_ws;
    unsigned short* aoutb = qkvb + 3 * (size_t)QKV1;
    float2*         pml   = (float2*)(aoutb + 4096 * 1024);
    unsigned short* Wt   = aoutb;
    unsigned short* Wt2  = qkvb;
    unsigned short* Xbf  = (unsigned short*)d_out;
    unsigned short* po   = (unsigned short*)d_out;

    // 128KB dynamic LDS opt-in (idempotent; no static guard — harness rule)
    (void)hipFuncSetAttribute((const void*)gemm256,
                              hipFuncAttributeMaxDynamicSharedMemorySize, 131072);

    cvt_f32_bf16<<<4096, 256, 0, stream>>>(x, Xbf, 4096 * 1024 / 4);
    transpose_cvt<<<dim3(96, 32), dim3(32, 8), 0, stream>>>(Wqkv, Wt, 1024, 3072);
    gemm256<<<192, 512, 131072, stream>>>(Xbf, Wt, bqkv, qkvb, 4096, 3072, 1024);
    attn_fwd<<<dim3(32, 32), 256, 0, stream>>>(qkvb, po, pml);
    attn_combine<<<1024, 256, 0, stream>>>(po, pml, aoutb);
    transpose_cvt<<<dim3(32, 32), dim3(32, 8), 0, stream>>>(Wproj, Wt2, 1024, 1024);
    gemm128<1><<<256, 256, 0, stream>>>(aoutb, Wt2, bproj, d_out, 4096, 1024, 1024);
}

// Round 15
// 129.996 us; speedup vs baseline: 1.0984x; 1.0984x over previous
//
#include <hip/hip_runtime.h>

typedef __bf16 bf16x8 __attribute__((ext_vector_type(8)));
typedef float f32x4 __attribute__((ext_vector_type(4)));
typedef float f32x16 __attribute__((ext_vector_type(16)));
typedef unsigned short u16x8 __attribute__((ext_vector_type(8)));

constexpr int S_LEN = 2048;
constexpr int QKV1  = 2 * 16 * 2048 * 64;   // elements per Q/K/V tensor = 4194304
#define LOG2E 1.44269504088896340736f

__device__ inline unsigned short f2bf(float f) {
    __bf16 h = (__bf16)f;
    return __builtin_bit_cast(unsigned short, h);
}

// global -> LDS async copy, 16B per lane; lds base must be wave-uniform,
// HW writes lane l at base + l*16 (m97/m104).
__device__ inline void gll16(const void* g, void* l) {
    __builtin_amdgcn_global_load_lds(
        (const __attribute__((address_space(1))) unsigned int*)g,
        (__attribute__((address_space(3))) unsigned int*)l,
        16, 0, 0);
}

// ---------------------------------------------------------------------------
// fp32 -> bf16 convert (for X).
// ---------------------------------------------------------------------------
__global__ __launch_bounds__(256) void cvt_f32_bf16(
    const float* __restrict__ src, unsigned short* __restrict__ dst, int n4)
{
    int i = blockIdx.x * 256 + threadIdx.x;
    if (i >= n4) return;
    float4 v = ((const float4*)src)[i];
    ushort4 u;
    u.x = f2bf(v.x); u.y = f2bf(v.y); u.z = f2bf(v.z); u.w = f2bf(v.w);
    ((ushort4*)dst)[i] = u;
}

// ---------------------------------------------------------------------------
// Transpose + convert: src [R][C] fp32 -> dst [C][R] bf16
// ---------------------------------------------------------------------------
__global__ __launch_bounds__(256) void transpose_cvt(
    const float* __restrict__ src, unsigned short* __restrict__ dst, int R, int C)
{
    __shared__ float t[32][33];
    const int c0 = blockIdx.x * 32, r0 = blockIdx.y * 32;
    const int tx = threadIdx.x, ty = threadIdx.y;
    #pragma unroll
    for (int i = 0; i < 4; ++i)
        t[ty * 4 + i][tx] = src[(size_t)(r0 + ty * 4 + i) * C + c0 + tx];
    __syncthreads();
    #pragma unroll
    for (int i = 0; i < 4; ++i)
        dst[(size_t)(c0 + ty * 4 + i) * R + r0 + tx] = f2bf(t[tx][ty * 4 + i]);
}

// ---------------------------------------------------------------------------
// bf16 GEMM, 2-phase double-buffered 128x128/BK=32 (REVERTED to R11 —
// measured best: 45.6us for QKV at 566 TF; 8-phase 256^2 port was slower
// at this grid (192 blocks = 75% CU fill) and is abandoned).
// EPI 0: qkv scatter; Q scaled by 0.125*log2e (exp2-domain softmax),
//        Q/K [bh][s][d], V transposed Vt[bh][d][s]. EPI 1: fp32 +bias.
// ---------------------------------------------------------------------------
template<int EPI>
__global__ __launch_bounds__(256) void gemm128(
    const unsigned short* __restrict__ A, const unsigned short* __restrict__ Bt,
    const float* __restrict__ bias, void* __restrict__ outp, int M, int N, int K)
{
    __shared__ unsigned short As[2][128 * 32];
    __shared__ unsigned short Bs[2][128 * 32];
    const int tid = threadIdx.x, lane = tid & 63, wid = tid >> 6;
    const int q = lane & 15, g = lane >> 4;
    const int wr = wid >> 1, wc = wid & 1;

    const int nbx = N >> 7;
    const int cpx = gridDim.x >> 3;
    const int bid = blockIdx.x;
    const int swz = (bid & 7) * cpx + (bid >> 3);    // bijective, nwg%8==0
    const int m0 = (swz / nbx) * 128, n0 = (swz % nbx) * 128;

    const int srow_in = lane >> 2;
    const int sslot   = (lane & 3) ^ (srow_in & 3);
    auto stage = [&](int buf, int k0) {
        #pragma unroll
        for (int i = 0; i < 2; ++i) {
            int c = wid * 2 + i;
            int row = c * 16 + srow_in;
            gll16(&A [(size_t)(m0 + row) * K + k0 + sslot * 8], &As[buf][c * 512]);
            gll16(&Bt[(size_t)(n0 + row) * K + k0 + sslot * 8], &Bs[buf][c * 512]);
        }
    };

    f32x4 acc[4][4];
    #pragma unroll
    for (int i = 0; i < 4; ++i)
        #pragma unroll
        for (int j = 0; j < 4; ++j) acc[i][j] = (f32x4){0.f, 0.f, 0.f, 0.f};

    const int NSTEP = K >> 5;
    const int rslot = (g ^ (q & 3)) * 8;             // read-side swizzle
    stage(0, 0);
    __syncthreads();
    int cur = 0;

    for (int ks = 0; ks < NSTEP; ++ks) {
        if (ks + 1 < NSTEP) stage(cur ^ 1, (ks + 1) * 32);  // fly under MFMA
        bf16x8 a[4], b[4];
        #pragma unroll
        for (int mi = 0; mi < 4; ++mi)
            a[mi] = *(const bf16x8*)&As[cur][(wr * 64 + mi * 16 + q) * 32 + rslot];
        #pragma unroll
        for (int ni = 0; ni < 4; ++ni)
            b[ni] = *(const bf16x8*)&Bs[cur][(wc * 64 + ni * 16 + q) * 32 + rslot];
        #pragma unroll
        for (int mi = 0; mi < 4; ++mi)
            #pragma unroll
            for (int ni = 0; ni < 4; ++ni)
                acc[mi][ni] = __builtin_amdgcn_mfma_f32_16x16x32_bf16(a[mi], b[ni], acc[mi][ni], 0, 0, 0);
        __syncthreads();                  // drains vmcnt (next buf ready) + lds
        cur ^= 1;
    }

    #pragma unroll
    for (int mi = 0; mi < 4; ++mi)
        #pragma unroll
        for (int ni = 0; ni < 4; ++ni)
            #pragma unroll
            for (int r = 0; r < 4; ++r) {
                int m = m0 + wr * 64 + mi * 16 + g * 4 + r;
                int n = n0 + wc * 64 + ni * 16 + q;
                float v = acc[mi][ni][r] + bias[n];
                if (EPI == 0) {
                    int t = n >> 10, rem = n & 1023;
                    if (t == 0) v *= 0.125f * LOG2E;  // q*rsqrt(64), log2 domain
                    int h2 = rem >> 6, kk = rem & 63;
                    int bb = m >> 11, s = m & 2047;
                    size_t off;
                    if (t == 2)   // V transposed: Vt[bh][d][s]
                        off = 2 * (size_t)QKV1 + ((size_t)(bb * 16 + h2) * 64 + kk) * 2048 + s;
                    else          // Q/K: [bh][s][d]
                        off = (size_t)t * QKV1 + ((size_t)(bb * 16 + h2) * 2048 + s) * 64 + kk;
                    ((unsigned short*)outp)[off] = f2bf(v);
                } else {
                    ((float*)outp)[(size_t)m * N + n] = v;
                }
            }
}

// ---------------------------------------------------------------------------
// Kernel 2: causal flash attention, KV-SPLIT (R11 structure; softmax now in
// exp2/log2 domain — scores arrive pre-scaled by log2e, so every exp is a
// bare v_exp_f32 with no v_mul).
// ---------------------------------------------------------------------------
__global__ __launch_bounds__(256) void attn_fwd(
    const unsigned short* __restrict__ qkv,
    unsigned short* __restrict__ po, float2* __restrict__ pml)
{
    __shared__ unsigned short Ks[2][64][72];
    __shared__ unsigned short Vs[2][64][72];
    __shared__ float cLds[4][32];
    const int tid = threadIdx.x, lane = tid & 63, wid = tid >> 6;
    const int hi = lane >> 5, lq = lane & 31;
    const int bh = blockIdx.x;
    const int uy = (int)blockIdx.y;
    const int t    = 15 - (uy >> 1);            // LPT: longest first
    const int half = uy & 1;
    const int jb0 = half ? (t + 1) : 0;
    const int jb1 = half ? (2 * t + 2) : (t + 1);
    const unsigned short* Qg = qkv + (size_t)bh * S_LEN * 64;
    const unsigned short* Kg = qkv + (size_t)QKV1 + (size_t)bh * S_LEN * 64;
    const unsigned short* Vt = qkv + 2 * (size_t)QKV1 + (size_t)bh * 64 * S_LEN;

    const int srr = tid >> 3, scc = (tid & 7) * 8;
    u16x8 kr[2], vr[2];
    auto stage_load = [&](int j0) {
        #pragma unroll
        for (int p = 0; p < 2; ++p) {
            kr[p] = *(const u16x8*)&Kg[(size_t)(j0 + srr + p * 32) * 64 + scc];
            vr[p] = *(const u16x8*)&Vt[(size_t)(srr + p * 32) * 2048 + j0 + scc];
        }
    };
    auto stage_write = [&](int b) {
        #pragma unroll
        for (int p = 0; p < 2; ++p) {
            *(u16x8*)&Ks[b][srr + p * 32][scc] = kr[p];
            *(u16x8*)&Vs[b][srr + p * 32][scc] = vr[p];
        }
    };

    const int qbase = t * 128 + wid * 32;
    const int qg = qbase + lq;

    bf16x8 qf[4];
    #pragma unroll
    for (int kc = 0; kc < 4; ++kc)
        qf[kc] = *(const bf16x8*)&Qg[(size_t)qg * 64 + kc * 16 + hi * 8];

    f32x16 z16;
    #pragma unroll
    for (int j = 0; j < 16; ++j) z16[j] = 0.f;

    f32x16 o0 = z16, o1 = z16;
    float m = -1e30f, lr = 0.f;      // lr = HALF-ROW partial; m in log2 units

    stage_load(jb0 * 64);
    stage_write(0);
    int cur = 0;

    for (int jb = jb0; jb < jb1; ++jb) {
        const int j0 = jb * 64;
        if (jb + 1 < jb1) stage_load(j0 + 64);
        __syncthreads();

        if (j0 <= qbase + 31) {
            f32x16 s0, s1;
            __builtin_amdgcn_s_setprio(1);
            {
                bf16x8 k0 = *(const bf16x8*)&Ks[cur][lq][hi * 8];
                bf16x8 k1 = *(const bf16x8*)&Ks[cur][32 + lq][hi * 8];
                s0 = __builtin_amdgcn_mfma_f32_32x32x16_bf16(k0, qf[0], z16, 0, 0, 0);
                s1 = __builtin_amdgcn_mfma_f32_32x32x16_bf16(k1, qf[0], z16, 0, 0, 0);
            }
            #pragma unroll
            for (int kc = 1; kc < 4; ++kc) {
                bf16x8 k0 = *(const bf16x8*)&Ks[cur][lq][kc * 16 + hi * 8];
                bf16x8 k1 = *(const bf16x8*)&Ks[cur][32 + lq][kc * 16 + hi * 8];
                s0 = __builtin_amdgcn_mfma_f32_32x32x16_bf16(k0, qf[kc], s0, 0, 0, 0);
                s1 = __builtin_amdgcn_mfma_f32_32x32x16_bf16(k1, qf[kc], s1, 0, 0, 0);
            }
            __builtin_amdgcn_s_setprio(0);
            if (j0 + 63 > qbase) {
                #pragma unroll
                for (int r = 0; r < 16; ++r) {
                    int kv0 = j0 + (r & 3) + 8 * (r >> 2) + 4 * hi;
                    if (kv0 > qg)      s0[r] = -1e30f;
                    if (kv0 + 32 > qg) s1[r] = -1e30f;
                }
            }
            float tm[8];
            #pragma unroll
            for (int j = 0; j < 8; ++j)
                tm[j] = fmaxf(fmaxf(s0[j], s0[j + 8]), fmaxf(s1[j], s1[j + 8]));
            float pm_loc = fmaxf(fmaxf(fmaxf(tm[0], tm[1]), fmaxf(tm[2], tm[3])),
                                 fmaxf(fmaxf(tm[4], tm[5]), fmaxf(tm[6], tm[7])));
            if (!__all(pm_loc <= m + 8.0f)) {
                float pm = fmaxf(pm_loc, __shfl_xor(pm_loc, 32));
                float mn = fmaxf(m, pm);
                float corr = exp2f(m - mn);
                m = mn; lr *= corr;
                if (lane < 32) cLds[wid][lq] = corr;
                #pragma unroll
                for (int r = 0; r < 16; ++r) {
                    float cq = cLds[wid][(r & 3) + 8 * (r >> 2) + 4 * hi];
                    o0[r] *= cq; o1[r] *= cq;
                }
            }
            float p0[16], p1[16], ts[16];
            #pragma unroll
            for (int j = 0; j < 16; ++j) {
                p0[j] = exp2f(s0[j] - m);
                p1[j] = exp2f(s1[j] - m);
                ts[j] = p0[j] + p1[j];
            }
            #pragma unroll
            for (int w = 8; w > 0; w >>= 1)
                #pragma unroll
                for (int j = 0; j < w; ++j) ts[j] += ts[j + w];
            lr += ts[0];
            int w0[8], w1[8];
            #pragma unroll
            for (int j = 0; j < 8; ++j) {
                asm("v_cvt_pk_bf16_f32 %0, %1, %2" : "=v"(w0[j]) : "v"(p0[2 * j]), "v"(p0[2 * j + 1]));
                asm("v_cvt_pk_bf16_f32 %0, %1, %2" : "=v"(w1[j]) : "v"(p1[2 * j]), "v"(p1[2 * j + 1]));
            }
            bf16x8 pa[4];
            auto mkfrag = [&](const int* w, int base) -> bf16x8 {
                int x0 = __shfl_xor(w[base + 0], 32);
                int x1 = __shfl_xor(w[base + 1], 32);
                int x2 = __shfl_xor(w[base + 2], 32);
                int x3 = __shfl_xor(w[base + 3], 32);
                int4 f;
                f.x = hi ? x2          : w[base + 0];
                f.y = hi ? x3          : w[base + 1];
                f.z = hi ? w[base + 2] : x0;
                f.w = hi ? w[base + 3] : x1;
                return __builtin_bit_cast(bf16x8, f);
            };
            pa[0] = mkfrag(w0, 0);
            pa[1] = mkfrag(w0, 4);
            pa[2] = mkfrag(w1, 0);
            pa[3] = mkfrag(w1, 4);
            __builtin_amdgcn_s_setprio(1);
            #pragma unroll
            for (int kc = 0; kc < 4; ++kc) {
                bf16x8 v0 = *(const bf16x8*)&Vs[cur][lq][kc * 16 + hi * 8];
                bf16x8 v1 = *(const bf16x8*)&Vs[cur][32 + lq][kc * 16 + hi * 8];
                o0 = __builtin_amdgcn_mfma_f32_32x32x16_bf16(pa[kc], v0, o0, 0, 0, 0);
                o1 = __builtin_amdgcn_mfma_f32_32x32x16_bf16(pa[kc], v1, o1, 0, 0, 0);
            }
            __builtin_amdgcn_s_setprio(0);
        }

        if (jb + 1 < jb1) stage_write(cur ^ 1);
        cur ^= 1;
    }

    const int unit = (bh * 16 + t) * 2 + half;
    float lr_full = lr + __shfl_xor(lr, 32);
    if (lane < 32) {
        float2 v; v.x = m; v.y = lr_full;   // m in log2 units (combine matches)
        pml[unit * 128 + wid * 32 + lq] = v;
    }
    #pragma unroll
    for (int r = 0; r < 16; ++r) {
        int lrow = wid * 32 + (r & 3) + 8 * (r >> 2) + 4 * hi;
        size_t off = ((size_t)unit * 128 + lrow) * 64;
        po[off + lq]      = f2bf(o0[r]);
        po[off + 32 + lq] = f2bf(o1[r]);
    }
}

// ---------------------------------------------------------------------------
// Combine: merge the two KV-halves per q-row (exp2 domain, matching attn).
// ---------------------------------------------------------------------------
__global__ __launch_bounds__(256) void attn_combine(
    const unsigned short* __restrict__ po, const float2* __restrict__ pml,
    unsigned short* __restrict__ aout)
{
    const int gid = blockIdx.x * 256 + threadIdx.x;
    const int row = gid >> 2;
    const int cg  = (gid & 3) * 16;
    const int bt = row >> 7, lrow = row & 127;
    const float2 ml0 = pml[(bt * 2 + 0) * 128 + lrow];
    const float2 ml1 = pml[(bt * 2 + 1) * 128 + lrow];
    const float ms = fmaxf(ml0.x, ml1.x);
    float w0 = exp2f(ml0.x - ms), w1 = exp2f(ml1.x - ms);
    const float inv = 1.0f / (ml0.y * w0 + ml1.y * w1);
    w0 *= inv; w1 *= inv;
    const size_t r0 = ((size_t)(bt * 2 + 0) * 128 + lrow) * 64 + cg;
    const size_t r1 = ((size_t)(bt * 2 + 1) * 128 + lrow) * 64 + cg;
    const int bh = bt >> 4, t = bt & 15;
    const int bb = bh >> 4, h = bh & 15;
    const int s = t * 128 + lrow;
    const size_t orow = ((size_t)(bb * 2048 + s)) * 1024 + h * 64 + cg;
    #pragma unroll
    for (int c = 0; c < 2; ++c) {
        u16x8 a = *(const u16x8*)&po[r0 + c * 8];
        u16x8 b = *(const u16x8*)&po[r1 + c * 8];
        u16x8 o;
        #pragma unroll
        for (int e = 0; e < 8; ++e) {
            float fa = __builtin_bit_cast(float, (unsigned)((unsigned short)a[e]) << 16);
            float fb = __builtin_bit_cast(float, (unsigned)((unsigned short)b[e]) << 16);
            o[e] = f2bf(fa * w0 + fb * w1);
        }
        *(u16x8*)&aout[orow + c * 8] = o;
    }
}

extern "C" void kernel_launch(void* const* d_in, const int* in_sizes, int n_in,
                              void* d_out, int out_size, void* d_ws, size_t ws_size,
                              hipStream_t stream) {
    const float* x     = (const float*)d_in[0];
    const float* Wqkv  = (const float*)d_in[2];
    const float* bqkv  = (const float*)d_in[3];
    const float* Wproj = (const float*)d_in[4];
    const float* bproj = (const float*)d_in[5];

    unsigned short* qkvb  = (unsigned short*)d_ws;           // Q,K [bh][s][d] + Vt [bh][d][s]
    unsigned short* aoutb = qkvb + 3 * (size_t)QKV1;         // 4096*1024 bf16
    float2*         pml   = (float2*)(aoutb + 4096 * 1024);  // 1024 units x 128 rows
    unsigned short* Wt   = aoutb;                  // W_qkv^T — dead once combine writes aoutb
    unsigned short* Wt2  = qkvb;                   // W_proj^T — qkv dead after attn
    unsigned short* Xbf  = (unsigned short*)d_out; // X bf16 — dead once gemm<0> done
    unsigned short* po   = (unsigned short*)d_out; // partial o bf16 — dead once combine done

    cvt_f32_bf16<<<4096, 256, 0, stream>>>(x, Xbf, 4096 * 1024 / 4);
    transpose_cvt<<<dim3(96, 32), dim3(32, 8), 0, stream>>>(Wqkv, Wt, 1024, 3072);
    gemm128<0><<<768, 256, 0, stream>>>(Xbf, Wt, bqkv, qkvb, 4096, 3072, 1024);
    attn_fwd<<<dim3(32, 32), 256, 0, stream>>>(qkvb, po, pml);
    attn_combine<<<1024, 256, 0, stream>>>(po, pml, aoutb);
    transpose_cvt<<<dim3(32, 32), dim3(32, 8), 0, stream>>>(Wproj, Wt2, 1024, 1024);
    gemm128<1><<<256, 256, 0, stream>>>(aoutb, Wt2, bproj, d_out, 4096, 1024, 1024);
}

// Round 16
// 123.046 us; speedup vs baseline: 1.1604x; 1.0565x over previous
//
#include <hip/hip_runtime.h>

typedef __bf16 bf16x8 __attribute__((ext_vector_type(8)));
typedef float f32x4 __attribute__((ext_vector_type(4)));
typedef float f32x16 __attribute__((ext_vector_type(16)));
typedef unsigned short u16x8 __attribute__((ext_vector_type(8)));

constexpr int S_LEN = 2048;
constexpr int QKV1  = 2 * 16 * 2048 * 64;   // elements per Q/K/V tensor = 4194304
#define LOG2E 1.44269504088896340736f

__device__ inline unsigned short f2bf(float f) {
    __bf16 h = (__bf16)f;
    return __builtin_bit_cast(unsigned short, h);
}

// Raw hardware exp2: ONE v_exp_f32 (no OCML range-fixup, no pre-multiply).
// For x << 0 (masked -1e30 entries) HW flushes to 0 — exactly what we want.
__device__ inline float fexp2(float x) {
    float r;
    asm("v_exp_f32 %0, %1" : "=v"(r) : "v"(x));
    return r;
}

// global -> LDS async copy, 16B per lane; lds base must be wave-uniform,
// HW writes lane l at base + l*16 (m97/m104).
__device__ inline void gll16(const void* g, void* l) {
    __builtin_amdgcn_global_load_lds(
        (const __attribute__((address_space(1))) unsigned int*)g,
        (__attribute__((address_space(3))) unsigned int*)l,
        16, 0, 0);
}

// ---------------------------------------------------------------------------
// fp32 -> bf16 convert (for X).
// ---------------------------------------------------------------------------
__global__ __launch_bounds__(256) void cvt_f32_bf16(
    const float* __restrict__ src, unsigned short* __restrict__ dst, int n4)
{
    int i = blockIdx.x * 256 + threadIdx.x;
    if (i >= n4) return;
    float4 v = ((const float4*)src)[i];
    ushort4 u;
    u.x = f2bf(v.x); u.y = f2bf(v.y); u.z = f2bf(v.z); u.w = f2bf(v.w);
    ((ushort4*)dst)[i] = u;
}

// ---------------------------------------------------------------------------
// Transpose + convert: src [R][C] fp32 -> dst [C][R] bf16
// ---------------------------------------------------------------------------
__global__ __launch_bounds__(256) void transpose_cvt(
    const float* __restrict__ src, unsigned short* __restrict__ dst, int R, int C)
{
    __shared__ float t[32][33];
    const int c0 = blockIdx.x * 32, r0 = blockIdx.y * 32;
    const int tx = threadIdx.x, ty = threadIdx.y;
    #pragma unroll
    for (int i = 0; i < 4; ++i)
        t[ty * 4 + i][tx] = src[(size_t)(r0 + ty * 4 + i) * C + c0 + tx];
    __syncthreads();
    #pragma unroll
    for (int i = 0; i < 4; ++i)
        dst[(size_t)(c0 + ty * 4 + i) * R + r0 + tx] = f2bf(t[tx][ty * 4 + i]);
}

// ---------------------------------------------------------------------------
// bf16 GEMM, 2-phase double-buffered 128x128/BK=32 (known-good, 566 TF).
// EPI 0: qkv scatter; Q scaled by 0.125*log2e (exp2-domain softmax),
//        Q/K [bh][s][d], V transposed Vt[bh][d][s]. EPI 1: fp32 +bias.
// ---------------------------------------------------------------------------
template<int EPI>
__global__ __launch_bounds__(256) void gemm128(
    const unsigned short* __restrict__ A, const unsigned short* __restrict__ Bt,
    const float* __restrict__ bias, void* __restrict__ outp, int M, int N, int K)
{
    __shared__ unsigned short As[2][128 * 32];
    __shared__ unsigned short Bs[2][128 * 32];
    const int tid = threadIdx.x, lane = tid & 63, wid = tid >> 6;
    const int q = lane & 15, g = lane >> 4;
    const int wr = wid >> 1, wc = wid & 1;

    const int nbx = N >> 7;
    const int cpx = gridDim.x >> 3;
    const int bid = blockIdx.x;
    const int swz = (bid & 7) * cpx + (bid >> 3);    // bijective, nwg%8==0
    const int m0 = (swz / nbx) * 128, n0 = (swz % nbx) * 128;

    const int srow_in = lane >> 2;
    const int sslot   = (lane & 3) ^ (srow_in & 3);
    auto stage = [&](int buf, int k0) {
        #pragma unroll
        for (int i = 0; i < 2; ++i) {
            int c = wid * 2 + i;
            int row = c * 16 + srow_in;
            gll16(&A [(size_t)(m0 + row) * K + k0 + sslot * 8], &As[buf][c * 512]);
            gll16(&Bt[(size_t)(n0 + row) * K + k0 + sslot * 8], &Bs[buf][c * 512]);
        }
    };

    f32x4 acc[4][4];
    #pragma unroll
    for (int i = 0; i < 4; ++i)
        #pragma unroll
        for (int j = 0; j < 4; ++j) acc[i][j] = (f32x4){0.f, 0.f, 0.f, 0.f};

    const int NSTEP = K >> 5;
    const int rslot = (g ^ (q & 3)) * 8;             // read-side swizzle
    stage(0, 0);
    __syncthreads();
    int cur = 0;

    for (int ks = 0; ks < NSTEP; ++ks) {
        if (ks + 1 < NSTEP) stage(cur ^ 1, (ks + 1) * 32);  // fly under MFMA
        bf16x8 a[4], b[4];
        #pragma unroll
        for (int mi = 0; mi < 4; ++mi)
            a[mi] = *(const bf16x8*)&As[cur][(wr * 64 + mi * 16 + q) * 32 + rslot];
        #pragma unroll
        for (int ni = 0; ni < 4; ++ni)
            b[ni] = *(const bf16x8*)&Bs[cur][(wc * 64 + ni * 16 + q) * 32 + rslot];
        #pragma unroll
        for (int mi = 0; mi < 4; ++mi)
            #pragma unroll
            for (int ni = 0; ni < 4; ++ni)
                acc[mi][ni] = __builtin_amdgcn_mfma_f32_16x16x32_bf16(a[mi], b[ni], acc[mi][ni], 0, 0, 0);
        __syncthreads();                  // drains vmcnt (next buf ready) + lds
        cur ^= 1;
    }

    #pragma unroll
    for (int mi = 0; mi < 4; ++mi)
        #pragma unroll
        for (int ni = 0; ni < 4; ++ni)
            #pragma unroll
            for (int r = 0; r < 4; ++r) {
                int m = m0 + wr * 64 + mi * 16 + g * 4 + r;
                int n = n0 + wc * 64 + ni * 16 + q;
                float v = acc[mi][ni][r] + bias[n];
                if (EPI == 0) {
                    int t = n >> 10, rem = n & 1023;
                    if (t == 0) v *= 0.125f * LOG2E;  // q*rsqrt(64), log2 domain
                    int h2 = rem >> 6, kk = rem & 63;
                    int bb = m >> 11, s = m & 2047;
                    size_t off;
                    if (t == 2)   // V transposed: Vt[bh][d][s]
                        off = 2 * (size_t)QKV1 + ((size_t)(bb * 16 + h2) * 64 + kk) * 2048 + s;
                    else          // Q/K: [bh][s][d]
                        off = (size_t)t * QKV1 + ((size_t)(bb * 16 + h2) * 2048 + s) * 64 + kk;
                    ((unsigned short*)outp)[off] = f2bf(v);
                } else {
                    ((float*)outp)[(size_t)m * N + n] = v;
                }
            }
}

// ---------------------------------------------------------------------------
// Kernel 2: causal flash attention, KV-SPLIT. exp2/log2-domain softmax with
// RAW v_exp_f32 (1 VALU op per exp; R15's exp2f libcall was ~7 ops — the
// measured VALUBusy 35->54% regression).
// ---------------------------------------------------------------------------
__global__ __launch_bounds__(256) void attn_fwd(
    const unsigned short* __restrict__ qkv,
    unsigned short* __restrict__ po, float2* __restrict__ pml)
{
    __shared__ unsigned short Ks[2][64][72];
    __shared__ unsigned short Vs[2][64][72];
    __shared__ float cLds[4][32];
    const int tid = threadIdx.x, lane = tid & 63, wid = tid >> 6;
    const int hi = lane >> 5, lq = lane & 31;
    const int bh = blockIdx.x;
    const int uy = (int)blockIdx.y;
    const int t    = 15 - (uy >> 1);            // LPT: longest first
    const int half = uy & 1;
    const int jb0 = half ? (t + 1) : 0;
    const int jb1 = half ? (2 * t + 2) : (t + 1);
    const unsigned short* Qg = qkv + (size_t)bh * S_LEN * 64;
    const unsigned short* Kg = qkv + (size_t)QKV1 + (size_t)bh * S_LEN * 64;
    const unsigned short* Vt = qkv + 2 * (size_t)QKV1 + (size_t)bh * 64 * S_LEN;

    const int srr = tid >> 3, scc = (tid & 7) * 8;
    u16x8 kr[2], vr[2];
    auto stage_load = [&](int j0) {
        #pragma unroll
        for (int p = 0; p < 2; ++p) {
            kr[p] = *(const u16x8*)&Kg[(size_t)(j0 + srr + p * 32) * 64 + scc];
            vr[p] = *(const u16x8*)&Vt[(size_t)(srr + p * 32) * 2048 + j0 + scc];
        }
    };
    auto stage_write = [&](int b) {
        #pragma unroll
        for (int p = 0; p < 2; ++p) {
            *(u16x8*)&Ks[b][srr + p * 32][scc] = kr[p];
            *(u16x8*)&Vs[b][srr + p * 32][scc] = vr[p];
        }
    };

    const int qbase = t * 128 + wid * 32;
    const int qg = qbase + lq;

    bf16x8 qf[4];
    #pragma unroll
    for (int kc = 0; kc < 4; ++kc)
        qf[kc] = *(const bf16x8*)&Qg[(size_t)qg * 64 + kc * 16 + hi * 8];

    f32x16 z16;
    #pragma unroll
    for (int j = 0; j < 16; ++j) z16[j] = 0.f;

    f32x16 o0 = z16, o1 = z16;
    float m = -1e30f, lr = 0.f;      // lr = HALF-ROW partial; m in log2 units

    stage_load(jb0 * 64);
    stage_write(0);
    int cur = 0;

    for (int jb = jb0; jb < jb1; ++jb) {
        const int j0 = jb * 64;
        if (jb + 1 < jb1) stage_load(j0 + 64);
        __syncthreads();

        if (j0 <= qbase + 31) {
            f32x16 s0, s1;
            __builtin_amdgcn_s_setprio(1);
            {
                bf16x8 k0 = *(const bf16x8*)&Ks[cur][lq][hi * 8];
                bf16x8 k1 = *(const bf16x8*)&Ks[cur][32 + lq][hi * 8];
                s0 = __builtin_amdgcn_mfma_f32_32x32x16_bf16(k0, qf[0], z16, 0, 0, 0);
                s1 = __builtin_amdgcn_mfma_f32_32x32x16_bf16(k1, qf[0], z16, 0, 0, 0);
            }
            #pragma unroll
            for (int kc = 1; kc < 4; ++kc) {
                bf16x8 k0 = *(const bf16x8*)&Ks[cur][lq][kc * 16 + hi * 8];
                bf16x8 k1 = *(const bf16x8*)&Ks[cur][32 + lq][kc * 16 + hi * 8];
                s0 = __builtin_amdgcn_mfma_f32_32x32x16_bf16(k0, qf[kc], s0, 0, 0, 0);
                s1 = __builtin_amdgcn_mfma_f32_32x32x16_bf16(k1, qf[kc], s1, 0, 0, 0);
            }
            __builtin_amdgcn_s_setprio(0);
            if (j0 + 63 > qbase) {
                #pragma unroll
                for (int r = 0; r < 16; ++r) {
                    int kv0 = j0 + (r & 3) + 8 * (r >> 2) + 4 * hi;
                    if (kv0 > qg)      s0[r] = -1e30f;
                    if (kv0 + 32 > qg) s1[r] = -1e30f;
                }
            }
            float tm[8];
            #pragma unroll
            for (int j = 0; j < 8; ++j)
                tm[j] = fmaxf(fmaxf(s0[j], s0[j + 8]), fmaxf(s1[j], s1[j + 8]));
            float pm_loc = fmaxf(fmaxf(fmaxf(tm[0], tm[1]), fmaxf(tm[2], tm[3])),
                                 fmaxf(fmaxf(tm[4], tm[5]), fmaxf(tm[6], tm[7])));
            if (!__all(pm_loc <= m + 8.0f)) {
                float pm = fmaxf(pm_loc, __shfl_xor(pm_loc, 32));
                float mn = fmaxf(m, pm);
                float corr = fexp2(m - mn);
                m = mn; lr *= corr;
                if (lane < 32) cLds[wid][lq] = corr;
                #pragma unroll
                for (int r = 0; r < 16; ++r) {
                    float cq = cLds[wid][(r & 3) + 8 * (r >> 2) + 4 * hi];
                    o0[r] *= cq; o1[r] *= cq;
                }
            }
            float p0[16], p1[16], ts[16];
            #pragma unroll
            for (int j = 0; j < 16; ++j) {
                p0[j] = fexp2(s0[j] - m);
                p1[j] = fexp2(s1[j] - m);
                ts[j] = p0[j] + p1[j];
            }
            #pragma unroll
            for (int w = 8; w > 0; w >>= 1)
                #pragma unroll
                for (int j = 0; j < w; ++j) ts[j] += ts[j + w];
            lr += ts[0];
            int w0[8], w1[8];
            #pragma unroll
            for (int j = 0; j < 8; ++j) {
                asm("v_cvt_pk_bf16_f32 %0, %1, %2" : "=v"(w0[j]) : "v"(p0[2 * j]), "v"(p0[2 * j + 1]));
                asm("v_cvt_pk_bf16_f32 %0, %1, %2" : "=v"(w1[j]) : "v"(p1[2 * j]), "v"(p1[2 * j + 1]));
            }
            bf16x8 pa[4];
            auto mkfrag = [&](const int* w, int base) -> bf16x8 {
                int x0 = __shfl_xor(w[base + 0], 32);
                int x1 = __shfl_xor(w[base + 1], 32);
                int x2 = __shfl_xor(w[base + 2], 32);
                int x3 = __shfl_xor(w[base + 3], 32);
                int4 f;
                f.x = hi ? x2          : w[base + 0];
                f.y = hi ? x3          : w[base + 1];
                f.z = hi ? w[base + 2] : x0;
                f.w = hi ? w[base + 3] : x1;
                return __builtin_bit_cast(bf16x8, f);
            };
            pa[0] = mkfrag(w0, 0);
            pa[1] = mkfrag(w0, 4);
            pa[2] = mkfrag(w1, 0);
            pa[3] = mkfrag(w1, 4);
            __builtin_amdgcn_s_setprio(1);
            #pragma unroll
            for (int kc = 0; kc < 4; ++kc) {
                bf16x8 v0 = *(const bf16x8*)&Vs[cur][lq][kc * 16 + hi * 8];
                bf16x8 v1 = *(const bf16x8*)&Vs[cur][32 + lq][kc * 16 + hi * 8];
                o0 = __builtin_amdgcn_mfma_f32_32x32x16_bf16(pa[kc], v0, o0, 0, 0, 0);
                o1 = __builtin_amdgcn_mfma_f32_32x32x16_bf16(pa[kc], v1, o1, 0, 0, 0);
            }
            __builtin_amdgcn_s_setprio(0);
        }

        if (jb + 1 < jb1) stage_write(cur ^ 1);
        cur ^= 1;
    }

    const int unit = (bh * 16 + t) * 2 + half;
    float lr_full = lr + __shfl_xor(lr, 32);
    if (lane < 32) {
        float2 v; v.x = m; v.y = lr_full;   // m in log2 units (combine matches)
        pml[unit * 128 + wid * 32 + lq] = v;
    }
    #pragma unroll
    for (int r = 0; r < 16; ++r) {
        int lrow = wid * 32 + (r & 3) + 8 * (r >> 2) + 4 * hi;
        size_t off = ((size_t)unit * 128 + lrow) * 64;
        po[off + lq]      = f2bf(o0[r]);
        po[off + 32 + lq] = f2bf(o1[r]);
    }
}

// ---------------------------------------------------------------------------
// Combine: merge the two KV-halves per q-row (exp2 domain, raw v_exp).
// ---------------------------------------------------------------------------
__global__ __launch_bounds__(256) void attn_combine(
    const unsigned short* __restrict__ po, const float2* __restrict__ pml,
    unsigned short* __restrict__ aout)
{
    const int gid = blockIdx.x * 256 + threadIdx.x;
    const int row = gid >> 2;
    const int cg  = (gid & 3) * 16;
    const int bt = row >> 7, lrow = row & 127;
    const float2 ml0 = pml[(bt * 2 + 0) * 128 + lrow];
    const float2 ml1 = pml[(bt * 2 + 1) * 128 + lrow];
    const float ms = fmaxf(ml0.x, ml1.x);
    float w0 = fexp2(ml0.x - ms), w1 = fexp2(ml1.x - ms);
    const float inv = 1.0f / (ml0.y * w0 + ml1.y * w1);
    w0 *= inv; w1 *= inv;
    const size_t r0 = ((size_t)(bt * 2 + 0) * 128 + lrow) * 64 + cg;
    const size_t r1 = ((size_t)(bt * 2 + 1) * 128 + lrow) * 64 + cg;
    const int bh = bt >> 4, t = bt & 15;
    const int bb = bh >> 4, h = bh & 15;
    const int s = t * 128 + lrow;
    const size_t orow = ((size_t)(bb * 2048 + s)) * 1024 + h * 64 + cg;
    #pragma unroll
    for (int c = 0; c < 2; ++c) {
        u16x8 a = *(const u16x8*)&po[r0 + c * 8];
        u16x8 b = *(const u16x8*)&po[r1 + c * 8];
        u16x8 o;
        #pragma unroll
        for (int e = 0; e < 8; ++e) {
            float fa = __builtin_bit_cast(float, (unsigned)((unsigned short)a[e]) << 16);
            float fb = __builtin_bit_cast(float, (unsigned)((unsigned short)b[e]) << 16);
            o[e] = f2bf(fa * w0 + fb * w1);
        }
        *(u16x8*)&aout[orow + c * 8] = o;
    }
}

extern "C" void kernel_launch(void* const* d_in, const int* in_sizes, int n_in,
                              void* d_out, int out_size, void* d_ws, size_t ws_size,
                              hipStream_t stream) {
    const float* x     = (const float*)d_in[0];
    const float* Wqkv  = (const float*)d_in[2];
    const float* bqkv  = (const float*)d_in[3];
    const float* Wproj = (const float*)d_in[4];
    const float* bproj = (const float*)d_in[5];

    unsigned short* qkvb  = (unsigned short*)d_ws;           // Q,K [bh][s][d] + Vt [bh][d][s]
    unsigned short* aoutb = qkvb + 3 * (size_t)QKV1;         // 4096*1024 bf16
    float2*         pml   = (float2*)(aoutb + 4096 * 1024);  // 1024 units x 128 rows
    unsigned short* Wt   = aoutb;                  // W_qkv^T — dead once combine writes aoutb
    unsigned short* Wt2  = qkvb;                   // W_proj^T — qkv dead after attn
    unsigned short* Xbf  = (unsigned short*)d_out; // X bf16 — dead once gemm<0> done
    unsigned short* po   = (unsigned short*)d_out; // partial o bf16 — dead once combine done

    cvt_f32_bf16<<<4096, 256, 0, stream>>>(x, Xbf, 4096 * 1024 / 4);
    transpose_cvt<<<dim3(96, 32), dim3(32, 8), 0, stream>>>(Wqkv, Wt, 1024, 3072);
    gemm128<0><<<768, 256, 0, stream>>>(Xbf, Wt, bqkv, qkvb, 4096, 3072, 1024);
    attn_fwd<<<dim3(32, 32), 256, 0, stream>>>(qkvb, po, pml);
    attn_combine<<<1024, 256, 0, stream>>>(po, pml, aoutb);
    transpose_cvt<<<dim3(32, 32), dim3(32, 8), 0, stream>>>(Wproj, Wt2, 1024, 1024);
    gemm128<1><<<256, 256, 0, stream>>>(aoutb, Wt2, bproj, d_out, 4096, 1024, 1024);
}